// Round 7
// baseline (62.268 us; speedup 1.0000x reference)
//
#include <hip/hip_runtime.h>
#include <cstddef>

typedef __attribute__((ext_vector_type(8))) short bf16x8;
typedef __attribute__((ext_vector_type(4))) unsigned short ushort4v;
typedef __attribute__((ext_vector_type(8))) unsigned short ushort8v;
typedef __attribute__((ext_vector_type(16))) float f32x16;

__device__ __forceinline__ unsigned short f2bf(float f) {
  union { float f; unsigned u; } v; v.f = f;
  unsigned r = v.u + 0x7FFFu + ((v.u >> 16) & 1u);  // round-to-nearest-even
  return (unsigned short)(r >> 16);
}

// ---------------- stage 1: x -> bf16 channel-last (zero-padded) + gap partials
// grid = 4096 blocks ((b,g,row-pair)), 256 threads.
// xt layout: [b][g][66 row][66 col][32 ic] bf16, 1-px zero halo.
#define PADC 132
__global__ __launch_bounds__(256) void prep_kernel(
    const float* __restrict__ x, unsigned short* __restrict__ xt,
    float* __restrict__ partials) {
  __shared__ unsigned short cm[32 * PADC];  // channel-major bf16: [ic][128 px]
  __shared__ float sred[32][32];
  const int bid = blockIdx.x;
  // XCD-chunked: same bg->XCD mapping as conv kernel (4096 % 8 == 0, bijective)
  const int wkr = ((bid & 7) << 9) | (bid >> 3);
  const int yp = wkr & 31, g = (wkr >> 5) & 7, b = wkr >> 8;
  const int y0 = yp * 2;
  const int tid = threadIdx.x;
  const float* xg = x + (size_t)(b * 256 + g * 32) * 4096;

  float csum[4];
#pragma unroll
  for (int j = 0; j < 4; ++j) {
    const int idx = tid + 256 * j;
    const int ic = idx >> 5;  // 0..31
    const int r = idx & 31;
    const int ry = r >> 4, gx4 = (r & 15) * 4;
    const float4 v = *reinterpret_cast<const float4*>(
        xg + (size_t)ic * 4096 + (y0 + ry) * 64 + gx4);
    csum[j] = v.x + v.y + v.z + v.w;
    ushort4v s;
    s[0] = f2bf(v.x); s[1] = f2bf(v.y); s[2] = f2bf(v.z); s[3] = f2bf(v.w);
    *reinterpret_cast<ushort4v*>(&cm[ic * PADC + ry * 64 + gx4]) = s;
  }
#pragma unroll
  for (int j = 0; j < 4; ++j) {
    const int ic = (tid >> 5) + 8 * j;
    sred[ic][tid & 31] = csum[j];
  }
  __syncthreads();

  if (tid < 32) {
    float s = 0.f;
#pragma unroll
    for (int i = 0; i < 32; ++i) s += sred[tid][i];
    partials[(size_t)(b * 256 + g * 32 + tid) * 32 + yp] = s;
  }

  const size_t xtb = (size_t)(b * 8 + g) * (66 * 66 * 32);
#pragma unroll
  for (int jj = 0; jj < 2; ++jj) {
    const int o = tid + 256 * jj;  // 0..511
    const int px = o >> 2, icq = o & 3;
    const int ry = px >> 6, gx = px & 63;
    ushort8v t;
#pragma unroll
    for (int c2 = 0; c2 < 8; ++c2) t[c2] = cm[(icq * 8 + c2) * PADC + px];
    *reinterpret_cast<ushort8v*>(
        &xt[xtb + ((size_t)(y0 + ry + 1) * 66 + (gx + 1)) * 32 + icq * 8]) = t;
  }

  const ushort8v z = {0, 0, 0, 0, 0, 0, 0, 0};
  if (tid < 16) {
    const int rr = tid >> 3;
    const int side = (tid >> 2) & 1;
    const int icq = tid & 3;
    const int col = side * 65;
    *reinterpret_cast<ushort8v*>(
        &xt[xtb + ((size_t)(y0 + rr + 1) * 66 + col) * 32 + icq * 8]) = z;
  }
  if (yp == 0 || yp == 31) {
    const int row = (yp == 0) ? 0 : 65;
    for (int o = tid; o < 66 * 4; o += 256) {
      const int col = o >> 2, icq = o & 3;
      *reinterpret_cast<ushort8v*>(
          &xt[xtb + ((size_t)row * 66 + col) * 32 + icq * 8]) = z;
    }
  }
}

// ---------------- stage 2: glgf prologue + conv main loop ----------------
// grid = 1024 blocks ((b,g,yq: 8 rows)), 256 threads = 4 waves, 2 blocks/CU
// (exact 2 rounds over 512 slots). A-fragments pinned in 72 VGPRs (asm);
// smem is a union: glgf wpack first, then B tile (chunk swizzle c'=c^(px&3)).
__global__ __launch_bounds__(256, 2) void conv_kernel(
    const float* __restrict__ partials,
    const float* __restrict__ w1l, const float* __restrict__ w1g1,
    const float* __restrict__ w1g2, const float* __restrict__ w2l,
    const float* __restrict__ w2g,
    const float* __restrict__ v1l, const float* __restrict__ v1g1,
    const float* __restrict__ v1g2, const float* __restrict__ v2l,
    const float* __restrict__ v2g,
    const unsigned short* __restrict__ xt, float* __restrict__ out) {
  __shared__ __align__(16) unsigned short smem[9216];  // wpack, then B tile
  __shared__ float gapL[256];
  __shared__ float hL[256];
  __shared__ float red[256];
  __shared__ float t1L[16];
  __shared__ float gateL[32];

  const int bid = blockIdx.x;
  const int wkr = ((bid & 7) << 7) | (bid >> 3);  // XCD-chunked, bijective
  const int yq = wkr & 7;
  const int bg = wkr >> 3;
  const int g = bg & 7, b = bg >> 3;
  const int tid = threadIdx.x;
  const int c = tid;

  // ---- gap from partials ----
  {
    float s = 0.f;
    const float* pp = partials + (size_t)(b * 256 + c) * 32;
#pragma unroll
    for (int i = 0; i < 32; ++i) s += pp[i];
    gapL[c] = s * (1.f / 4096.f);
  }
  __syncthreads();

  // ---- generator 1: h1, glob2 ----
  const int gbase = c & ~15;
  float local1 = 0.f;
#pragma unroll
  for (int i = 0; i < 16; ++i) local1 += gapL[gbase + i] * w1l[c * 16 + i];
  if (c < 16) {
    float t = 0.f;
#pragma unroll
    for (int i = 0; i < 16; ++i) t += gapL[c * 16 + i] * w1g1[c * 16 + i];
    t1L[c] = t;
  }
  __syncthreads();
  float glob1 = 0.f;
#pragma unroll
  for (int gg = 0; gg < 16; ++gg) glob1 += t1L[gg] * w1g2[c * 16 + gg];
  const float h1 = 1.f / (1.f + expf(-(local1 + glob1)));
  hL[c] = h1;
  red[c] = h1 * w2g[c];
  __syncthreads();
  for (int s = 128; s > 0; s >>= 1) {
    if (c < s) red[c] += red[c + s];
    __syncthreads();
  }
  const float glob2 = red[0];
  __syncthreads();

  // ---- pack A fragments for this (b,g) into smem (wpack view) ----
#pragma unroll 4
  for (int it = 0; it < 36; ++it) {
    const int idx = it * 256 + c;  // 0..9215
    const int kk = idx >> 9;
    const int rem = idx & 511;
    const int l = rem >> 3, e = rem & 7;
    const int oc = l & 31, hi2 = l >> 5;
    const int ic = ((kk & 1) << 4) + hi2 * 8 + e;
    const int sp = kk >> 1;
    const int o = (g << 5) + oc;
    smem[idx] = f2bf(hL[o] * w2l[o * 288 + ic * 9 + sp] + glob2);
  }
  __syncthreads();  // wpack ready; hL free to overwrite

  // ---- generator 2: gate ----
  float local2 = 0.f;
#pragma unroll
  for (int i = 0; i < 16; ++i) local2 += gapL[gbase + i] * v1l[c * 16 + i];
  if (c < 16) {
    float t = 0.f;
#pragma unroll
    for (int i = 0; i < 16; ++i) t += gapL[c * 16 + i] * v1g1[c * 16 + i];
    t1L[c] = t;
  }
  __syncthreads();
  float glob1b = 0.f;
#pragma unroll
  for (int gg = 0; gg < 16; ++gg) glob1b += t1L[gg] * v1g2[c * 16 + gg];
  const float h2 = 1.f / (1.f + expf(-(local2 + glob1b)));
  hL[c] = h2;
  red[c] = h2 * v2g[c];
  __syncthreads();
  for (int s = 128; s > 0; s >>= 1) {
    if (c < s) red[c] += red[c + s];
    __syncthreads();
  }
  if (c < 32) {
    const int o = g * 32 + c;
    gateL[c] = hL[o] * v2l[o] + red[0];
  }

  // ---- A fragments -> registers, pinned so they can't sink back to LDS ----
  const int lane = tid & 63, wave = tid >> 6;
  const int n = lane & 31, hi = lane >> 5;
  const int wr = wave >> 1, wc = wave & 1;
  const size_t xtb = (size_t)bg * (66 * 66 * 32);

  bf16x8 a[18];
#pragma unroll
  for (int kk = 0; kk < 18; ++kk) {
    a[kk] = *reinterpret_cast<const bf16x8*>(&smem[kk * 512 + lane * 8]);
    asm volatile("" : "+v"(a[kk]));  // force VGPR residency (R6: compiler sank)
  }
  __syncthreads();  // all waves done reading wpack; smem becomes B tile

  // per-thread staging slots (1056 ushort8 per tile / 256 threads -> 5 w/ pred)
  int s_live[5], s_goff[5], s_loff[5];
#pragma unroll
  for (int s = 0; s < 5; ++s) {
    const int li = s * 256 + tid;
    s_live[s] = li < 1056;
    const int r = li / 264;
    const int rem = li - r * 264;
    const int px = rem >> 2, cq = rem & 3;
    s_goff[s] = ((yq * 8 + r) * 66 + px) * 32 + cq * 8;
    s_loff[s] = (((r << 2) + (cq ^ (px & 3))) * 66 + px) * 8;
  }
  ushort8v st[5];

  // preload p=0
#pragma unroll
  for (int s = 0; s < 5; ++s)
    if (s_live[s])
      st[s] = *reinterpret_cast<const ushort8v*>(&xt[xtb + s_goff[s]]);

#pragma unroll 1
  for (int p = 0; p < 4; ++p) {
    // write staged regs -> B tile (swizzled)
#pragma unroll
    for (int s = 0; s < 5; ++s)
      if (s_live[s])
        *reinterpret_cast<ushort8v*>(&smem[s_loff[s]]) = st[s];
    __syncthreads();

    // issue next tile's global loads (hide under MFMA phase)
    if (p < 3) {
#pragma unroll
      for (int s = 0; s < 5; ++s)
        if (s_live[s])
          st[s] = *reinterpret_cast<const ushort8v*>(
              &xt[xtb + s_goff[s] + (p + 1) * 2 * 66 * 32]);
    }

    f32x16 acc;
#pragma unroll
    for (int i = 0; i < 16; ++i) acc[i] = 0.f;
#pragma unroll
    for (int kk = 0; kk < 18; ++kk) {
      const int sp = kk >> 1;
      const int ky = sp / 3, kx = sp % 3;
      const int px2 = wc * 32 + n + kx;
      const int cq = ((kk & 1) << 1) + hi;
      const bf16x8 bf = *reinterpret_cast<const bf16x8*>(
          &smem[((((wr + ky) << 2) + (cq ^ (px2 & 3))) * 66 + px2) * 8]);
      acc = __builtin_amdgcn_mfma_f32_32x32x16_bf16(a[kk], bf, acc, 0, 0, 0);
    }

    const int y = yq * 8 + p * 2 + wr;
    float* ob = out + (size_t)(b * 256 + g * 32) * 4096 + y * 64 + wc * 32 + n;
#pragma unroll
    for (int r = 0; r < 16; ++r) {
      const int row = (r & 3) + ((r >> 2) << 3) + (hi << 2);
      ob[(size_t)row * 4096] = acc[r] * gateL[row];
    }
    __syncthreads();  // B tile consumed; safe to overwrite next p
  }
}

extern "C" void kernel_launch(void* const* d_in, const int* in_sizes, int n_in,
                              void* d_out, int out_size, void* d_ws,
                              size_t ws_size, hipStream_t stream) {
  const float* x    = (const float*)d_in[0];
  const float* w1l  = (const float*)d_in[1];
  const float* w1g1 = (const float*)d_in[2];
  const float* w1g2 = (const float*)d_in[3];
  const float* w2l  = (const float*)d_in[4];
  const float* w2g  = (const float*)d_in[5];
  const float* v1l  = (const float*)d_in[6];
  const float* v1g1 = (const float*)d_in[7];
  const float* v1g2 = (const float*)d_in[8];
  const float* v2l  = (const float*)d_in[9];
  const float* v2g  = (const float*)d_in[10];
  float* out = (float*)d_out;

  unsigned short* xt = (unsigned short*)d_ws;   // 17,842,176 bf16
  float* partials = (float*)(xt + 17842176);    // 131,072 f32

  prep_kernel<<<4096, 256, 0, stream>>>(x, xt, partials);
  conv_kernel<<<1024, 256, 0, stream>>>(partials, w1l, w1g1, w1g2, w2l, w2g,
                                        v1l, v1g1, v1g2, v2l, v2g, xt, out);
}

// Round 8
// 50.594 us; speedup vs baseline: 1.2307x; 1.2307x over previous
//
#include <hip/hip_runtime.h>
#include <cstddef>

typedef __attribute__((ext_vector_type(8))) short bf16x8;
typedef __attribute__((ext_vector_type(4))) unsigned short ushort4v;
typedef __attribute__((ext_vector_type(8))) unsigned short ushort8v;
typedef __attribute__((ext_vector_type(16))) float f32x16;

__device__ __forceinline__ unsigned short f2bf(float f) {
  union { float f; unsigned u; } v; v.f = f;
  unsigned r = v.u + 0x7FFFu + ((v.u >> 16) & 1u);  // round-to-nearest-even
  return (unsigned short)(r >> 16);
}

// ---------------- stage 1: x -> bf16 channel-last (zero-padded) + gap partials
// grid = 4096 blocks ((b,g,row-pair)), 256 threads.
// xt layout: [b][g][66 row][66 col][32 ic] bf16, 1-px zero halo.
#define PADC 132
__global__ __launch_bounds__(256) void prep_kernel(
    const float* __restrict__ x, unsigned short* __restrict__ xt,
    float* __restrict__ partials) {
  __shared__ unsigned short cm[32 * PADC];  // channel-major bf16: [ic][128 px]
  __shared__ float sred[32][32];
  const int bid = blockIdx.x;
  // XCD-chunked: xt[bg] written on XCD bg>>4 (matches conv reader)
  const int wkr = ((bid & 7) << 9) | (bid >> 3);
  const int yp = wkr & 31, g = (wkr >> 5) & 7, b = wkr >> 8;
  const int y0 = yp * 2;
  const int tid = threadIdx.x;
  const float* xg = x + (size_t)(b * 256 + g * 32) * 4096;

  float csum[4];
#pragma unroll
  for (int j = 0; j < 4; ++j) {
    const int idx = tid + 256 * j;
    const int ic = idx >> 5;  // 0..31
    const int r = idx & 31;
    const int ry = r >> 4, gx4 = (r & 15) * 4;
    const float4 v = *reinterpret_cast<const float4*>(
        xg + (size_t)ic * 4096 + (y0 + ry) * 64 + gx4);
    csum[j] = v.x + v.y + v.z + v.w;
    ushort4v s;
    s[0] = f2bf(v.x); s[1] = f2bf(v.y); s[2] = f2bf(v.z); s[3] = f2bf(v.w);
    *reinterpret_cast<ushort4v*>(&cm[ic * PADC + ry * 64 + gx4]) = s;
  }
#pragma unroll
  for (int j = 0; j < 4; ++j) {
    const int ic = (tid >> 5) + 8 * j;
    sred[ic][tid & 31] = csum[j];
  }
  __syncthreads();

  if (tid < 32) {
    float s = 0.f;
#pragma unroll
    for (int i = 0; i < 32; ++i) s += sred[tid][i];
    partials[(size_t)(b * 256 + g * 32 + tid) * 32 + yp] = s;
  }

  const size_t xtb = (size_t)(b * 8 + g) * (66 * 66 * 32);
#pragma unroll
  for (int jj = 0; jj < 2; ++jj) {
    const int o = tid + 256 * jj;  // 0..511
    const int px = o >> 2, icq = o & 3;
    const int ry = px >> 6, gx = px & 63;
    ushort8v t;
#pragma unroll
    for (int c2 = 0; c2 < 8; ++c2) t[c2] = cm[(icq * 8 + c2) * PADC + px];
    *reinterpret_cast<ushort8v*>(
        &xt[xtb + ((size_t)(y0 + ry + 1) * 66 + (gx + 1)) * 32 + icq * 8]) = t;
  }

  const ushort8v z = {0, 0, 0, 0, 0, 0, 0, 0};
  if (tid < 16) {
    const int rr = tid >> 3;
    const int side = (tid >> 2) & 1;
    const int icq = tid & 3;
    const int col = side * 65;
    *reinterpret_cast<ushort8v*>(
        &xt[xtb + ((size_t)(y0 + rr + 1) * 66 + col) * 32 + icq * 8]) = z;
  }
  if (yp == 0 || yp == 31) {
    const int row = (yp == 0) ? 0 : 65;
    for (int o = tid; o < 66 * 4; o += 256) {
      const int col = o >> 2, icq = o & 3;
      *reinterpret_cast<ushort8v*>(
          &xt[xtb + ((size_t)row * 66 + col) * 32 + icq * 8]) = z;
    }
  }
}

// ---------------- stage 2: glgf weight/gate generation (once per (b,g)) ----
// grid = 128 blocks, 256 threads. bg remapped so wpack[bg] is produced on
// XCD bg>>4 — the same XCD conv reads it from.
__global__ __launch_bounds__(256) void glgf_pack(
    const float* __restrict__ partials,
    const float* __restrict__ w1l, const float* __restrict__ w1g1,
    const float* __restrict__ w1g2, const float* __restrict__ w2l,
    const float* __restrict__ w2g,
    const float* __restrict__ v1l, const float* __restrict__ v1g1,
    const float* __restrict__ v1g2, const float* __restrict__ v2l,
    const float* __restrict__ v2g,
    unsigned short* __restrict__ wpack, float* __restrict__ gate) {
  __shared__ float gapL[256];
  __shared__ float t1L[16];
  __shared__ float hL[256];
  __shared__ float red[256];
  const int bid = blockIdx.x;
  const int bg = ((bid & 7) << 4) | (bid >> 3);  // block on XCD bg>>4
  const int g = bg & 7, b = bg >> 3;
  const int c = threadIdx.x;
  {
    float s = 0.f;
    const float* pp = partials + (size_t)(b * 256 + c) * 32;
#pragma unroll
    for (int i = 0; i < 32; ++i) s += pp[i];
    gapL[c] = s * (1.f / 4096.f);
  }
  __syncthreads();

  const int gbase = c & ~15;
  float local1 = 0.f;
#pragma unroll
  for (int i = 0; i < 16; ++i) local1 += gapL[gbase + i] * w1l[c * 16 + i];
  if (c < 16) {
    float t = 0.f;
#pragma unroll
    for (int i = 0; i < 16; ++i) t += gapL[c * 16 + i] * w1g1[c * 16 + i];
    t1L[c] = t;
  }
  __syncthreads();
  float glob1 = 0.f;
#pragma unroll
  for (int gg = 0; gg < 16; ++gg) glob1 += t1L[gg] * w1g2[c * 16 + gg];
  const float h1 = 1.f / (1.f + expf(-(local1 + glob1)));
  hL[c] = h1;
  red[c] = h1 * w2g[c];
  __syncthreads();
  for (int s = 128; s > 0; s >>= 1) {
    if (c < s) red[c] += red[c + s];
    __syncthreads();
  }
  const float glob2 = red[0];

  unsigned short* wpo = wpack + (size_t)bg * 9216;
#pragma unroll 4
  for (int it = 0; it < 36; ++it) {
    const int idx = it * 256 + c;
    const int kk = idx >> 9;
    const int rem = idx & 511;
    const int l = rem >> 3, e = rem & 7;
    const int oc = l & 31, hi = l >> 5;
    const int ic = ((kk & 1) << 4) + hi * 8 + e;
    const int sp = kk >> 1;
    const int o = (g << 5) + oc;
    wpo[idx] = f2bf(hL[o] * w2l[o * 288 + ic * 9 + sp] + glob2);
  }

  if (g == 0) {
    __syncthreads();
    float local2 = 0.f;
#pragma unroll
    for (int i = 0; i < 16; ++i) local2 += gapL[gbase + i] * v1l[c * 16 + i];
    if (c < 16) {
      float t = 0.f;
#pragma unroll
      for (int i = 0; i < 16; ++i) t += gapL[c * 16 + i] * v1g1[c * 16 + i];
      t1L[c] = t;
    }
    __syncthreads();
    float glob1b = 0.f;
#pragma unroll
    for (int gg = 0; gg < 16; ++gg) glob1b += t1L[gg] * v1g2[c * 16 + gg];
    const float h2 = 1.f / (1.f + expf(-(local2 + glob1b)));
    red[c] = h2 * v2g[c];
    __syncthreads();
    for (int s = 128; s > 0; s >>= 1) {
      if (c < s) red[c] += red[c + s];
      __syncthreads();
    }
    gate[b * 256 + c] = h2 * v2l[c] + red[0];
  }
}

// ---------------- stage 3: conv, deferred stores, no store-drain barriers ----
// grid = 1024 blocks ((b,g,yq: 8 rows)), 256 threads = 4 waves, 4 blocks/CU.
// A frags in wpl LDS (2 reads/MFMA); acc[4] deferred -> stores only at end.
__global__ __launch_bounds__(256, 4) void conv_kernel(
    const unsigned short* __restrict__ wpack, const float* __restrict__ gate,
    const unsigned short* __restrict__ xt, float* __restrict__ out) {
  __shared__ __align__(16) unsigned short wpl[9216];   // 18432 B
  __shared__ __align__(16) unsigned short btile[8448]; // 16896 B
  __shared__ float gateL[32];

  const int bid = blockIdx.x;
  const int wkr = ((bid & 7) << 7) | (bid >> 3);  // XCD-chunked, bijective
  const int yq = wkr & 7;
  const int bg = wkr >> 3;
  const int g = bg & 7, b = bg >> 3;
  const int tid = threadIdx.x;

  const int lane = tid & 63;
  const int n = lane & 31, hi = lane >> 5;
  const int wave = tid >> 6;
  const int wr = wave >> 1, wc = wave & 1;
  const size_t xtb = (size_t)bg * (66 * 66 * 32);

  // ---- prologue: wpack -> wpl (linear 16B copy), gate -> gateL ----
  {
    const uint4* src = reinterpret_cast<const uint4*>(wpack + (size_t)bg * 9216);
    uint4* dst = reinterpret_cast<uint4*>(wpl);
    for (int i = tid; i < 1152; i += 256) dst[i] = src[i];
  }
  if (tid < 32) gateL[tid] = gate[b * 256 + g * 32 + tid];

  // ---- staging slots (1056 ushort8 per tile / 256 threads -> 5 w/ pred) ----
  int s_live[5], s_goff[5], s_loff[5];
#pragma unroll
  for (int s = 0; s < 5; ++s) {
    const int li = s * 256 + tid;
    s_live[s] = li < 1056;
    const int r = li / 264;
    const int rem = li - r * 264;
    const int px = rem >> 2, cq = rem & 3;
    s_goff[s] = ((yq * 8 + r) * 66 + px) * 32 + cq * 8;
    s_loff[s] = (((r << 2) + (cq ^ (px & 3))) * 66 + px) * 8;
  }
  ushort8v st[5];

  // load + write p=0 tile before the single prologue barrier
#pragma unroll
  for (int s = 0; s < 5; ++s)
    if (s_live[s])
      st[s] = *reinterpret_cast<const ushort8v*>(&xt[xtb + s_goff[s]]);
#pragma unroll
  for (int s = 0; s < 5; ++s)
    if (s_live[s]) *reinterpret_cast<ushort8v*>(&btile[s_loff[s]]) = st[s];

  __syncthreads();  // wpl + gateL + btile(p0) visible

  f32x16 acc[4];
#pragma unroll
  for (int p = 0; p < 4; ++p) {
    if (p > 0) {
      // st holds tile p (prefetched during p-1 compute)
#pragma unroll
      for (int s = 0; s < 5; ++s)
        if (s_live[s]) *reinterpret_cast<ushort8v*>(&btile[s_loff[s]]) = st[s];
      __syncthreads();  // writes visible (LDS-only drain; no global stores yet)
    }

    // prefetch tile p+1 (lands during MFMA phase)
    if (p < 3) {
#pragma unroll
      for (int s = 0; s < 5; ++s)
        if (s_live[s])
          st[s] = *reinterpret_cast<const ushort8v*>(
              &xt[xtb + s_goff[s] + (p + 1) * 2 * 66 * 32]);
    }

#pragma unroll
    for (int i = 0; i < 16; ++i) acc[p][i] = 0.f;
#pragma unroll
    for (int kk = 0; kk < 18; ++kk) {
      const int sp = kk >> 1;
      const int ky = sp / 3, kx = sp % 3;
      const int px2 = wc * 32 + n + kx;
      const int cq = ((kk & 1) << 1) + hi;
      const bf16x8 af =
          *reinterpret_cast<const bf16x8*>(&wpl[kk * 512 + lane * 8]);
      const bf16x8 bf = *reinterpret_cast<const bf16x8*>(
          &btile[((((wr + ky) << 2) + (cq ^ (px2 & 3))) * 66 + px2) * 8]);
      acc[p] = __builtin_amdgcn_mfma_f32_32x32x16_bf16(af, bf, acc[p], 0, 0, 0);
    }

    if (p < 3) __syncthreads();  // all reads of tile p done before overwrite
  }

  // ---- epilogue: all stores at the very end; no barrier follows ----
  float* ob0 = out + (size_t)(b * 256 + g * 32) * 4096 + wc * 32 + n;
#pragma unroll
  for (int p = 0; p < 4; ++p) {
    const int y = yq * 8 + p * 2 + wr;
    float* ob = ob0 + y * 64;
#pragma unroll
    for (int r = 0; r < 16; ++r) {
      const int row = (r & 3) + ((r >> 2) << 3) + (hi << 2);
      ob[(size_t)row * 4096] = acc[p][r] * gateL[row];
    }
  }
}

extern "C" void kernel_launch(void* const* d_in, const int* in_sizes, int n_in,
                              void* d_out, int out_size, void* d_ws,
                              size_t ws_size, hipStream_t stream) {
  const float* x    = (const float*)d_in[0];
  const float* w1l  = (const float*)d_in[1];
  const float* w1g1 = (const float*)d_in[2];
  const float* w1g2 = (const float*)d_in[3];
  const float* w2l  = (const float*)d_in[4];
  const float* w2g  = (const float*)d_in[5];
  const float* v1l  = (const float*)d_in[6];
  const float* v1g1 = (const float*)d_in[7];
  const float* v1g2 = (const float*)d_in[8];
  const float* v2l  = (const float*)d_in[9];
  const float* v2g  = (const float*)d_in[10];
  float* out = (float*)d_out;

  unsigned short* xt = (unsigned short*)d_ws;      // 17,842,176 bf16
  float* partials = (float*)(xt + 17842176);       // 131,072 f32
  unsigned short* wpack = (unsigned short*)(partials + 131072);  // 1,179,648 bf16
  float* gate = (float*)(wpack + 1179648);         // 4,096 f32

  prep_kernel<<<4096, 256, 0, stream>>>(x, xt, partials);
  glgf_pack<<<128, 256, 0, stream>>>(partials, w1l, w1g1, w1g2, w2l, w2g,
                                     v1l, v1g1, v1g2, v2l, v2g, wpack, gate);
  conv_kernel<<<1024, 256, 0, stream>>>(wpack, gate, xt, out);
}